// Round 2
// baseline (2052.073 us; speedup 1.0000x reference)
//
#include <hip/hip_runtime.h>
#include <stdint.h>

// ---------------------------------------------------------------------------
// FakeNewsModel: 3-layer GraphSAGE (mean agg), N=50000, E=1.6M, width 64.
// Round 2: dtype-adaptive correctness build.
//   k_detect  -> flags[0]=floats-are-bf16?, flags[1]=ints-are-int64?
//   CSR build -> memset(cnt), k_deg, k_scan1/2/3, k_scatter
//   k_project -> x0 = concat(xc@Wp+bp, xs@Ws+bs)  (fp32 h-table)
//   k_layer x3 -> relu(mean-agg@Wl + bl + x@Wr); layer 3 fuses [64,2] head.
// All gather indices clamped to [0,N) so no world produces NaN/faults.
// ---------------------------------------------------------------------------

static __device__ __forceinline__ float bf2f(unsigned short u) {
  union { unsigned int i; float f; } v;
  v.i = ((unsigned int)u) << 16;
  return v.f;
}

static __device__ __forceinline__ unsigned short f2bf(float f) {
  union { float f; unsigned int i; } v;
  v.f = f;
  unsigned int u = v.i;
  unsigned int r = (u + 0x7FFFu + ((u >> 16) & 1u)) >> 16;  // RNE
  return (unsigned short)r;
}

template <bool BF>
static __device__ __forceinline__ float ldf(const void* p, long long i) {
  if (BF) return bf2f(((const unsigned short*)p)[i]);
  return ((const float*)p)[i];
}

static __device__ __forceinline__ int clampN(int v, int N) {
  return v < 0 ? 0 : (v >= N ? N - 1 : v);
}

// ---------------- dtype detection ----------------
// flags[0] = 1 if float tensors are bf16 (ushort), 0 if fp32.
//   bf16 Wp values are U(-0.036,0.036); fp32-read-as-bf16 hits |v|>=1 or NaN
//   among 64 consecutive ushorts with prob ~1-3e-20.
// flags[1] = 1 if int tensors are int64 (odd int32 words of values<2^31 are 0),
//   0 if int32 (odd words are random dst/src values, all-zero prob ~0).
__global__ void k_detect(const void* Wp, const int* ei, int* flags) {
  if (threadIdx.x == 0 && blockIdx.x == 0) {
    const unsigned short* w = (const unsigned short*)Wp;
    int bf = 1;
    for (int i = 0; i < 64; ++i) {
      float v = fabsf(bf2f(w[i]));
      if (!(v < 1.0f)) bf = 0;  // catches NaN too
    }
    flags[0] = bf;
    int i64 = 1;
    for (int i = 0; i < 32; ++i)
      if (ei[2 * i + 1] != 0) i64 = 0;
    flags[1] = i64;
  }
}

static __device__ __forceinline__ int edge_src(const int* ei, int e, int E,
                                               int i64) {
  return i64 ? ei[2 * (long long)e] : ei[e];
}
static __device__ __forceinline__ int edge_dst(const int* ei, int e, int E,
                                               int i64) {
  return i64 ? ei[2 * ((long long)E + e)] : ei[(long long)E + e];
}

// ---------------- CSR build ----------------

__global__ __launch_bounds__(256) void k_deg(const int* __restrict__ ei, int E,
                                             int N, int* __restrict__ cnt,
                                             const int* __restrict__ flags) {
  int e = blockIdx.x * 256 + threadIdx.x;
  if (e < E) {
    int d = clampN(edge_dst(ei, e, E, flags[1]), N);
    atomicAdd(&cnt[d], 1);
  }
}

__global__ __launch_bounds__(256) void k_scan1(const int* __restrict__ cnt,
                                               int* __restrict__ rowptr,
                                               int* __restrict__ bsum, int N) {
  __shared__ int sh[256];
  int t = threadIdx.x;
  int base = blockIdx.x * 1024 + t * 4;
  int v0 = 0, v1 = 0, v2 = 0, v3 = 0;
  if (base + 0 < N) v0 = cnt[base + 0];
  if (base + 1 < N) v1 = cnt[base + 1];
  if (base + 2 < N) v2 = cnt[base + 2];
  if (base + 3 < N) v3 = cnt[base + 3];
  int s = v0 + v1 + v2 + v3;
  sh[t] = s;
  __syncthreads();
  int acc = s;
  for (int off = 1; off < 256; off <<= 1) {
    int x = 0;
    if (t >= off) x = sh[t - off];
    __syncthreads();
    acc += x;
    sh[t] = acc;
    __syncthreads();
  }
  int run = acc - s;
  if (base + 0 < N) rowptr[base + 0] = run;
  run += v0;
  if (base + 1 < N) rowptr[base + 1] = run;
  run += v1;
  if (base + 2 < N) rowptr[base + 2] = run;
  run += v2;
  if (base + 3 < N) rowptr[base + 3] = run;
  run += v3;
  if (t == 255) bsum[blockIdx.x] = acc;
}

__global__ void k_scan2(int* __restrict__ bsum, int nb,
                        int* __restrict__ rowptr, int N) {
  if (threadIdx.x == 0 && blockIdx.x == 0) {
    int run = 0;
    for (int i = 0; i < nb; ++i) {
      int v = bsum[i];
      bsum[i] = run;
      run += v;
    }
    rowptr[N] = run;
  }
}

__global__ __launch_bounds__(256) void k_scan3(int* __restrict__ rowptr,
                                               int* __restrict__ cursor,
                                               const int* __restrict__ bsum,
                                               int N) {
  int i = blockIdx.x * 256 + threadIdx.x;
  if (i < N) {
    int v = rowptr[i] + bsum[i >> 10];
    rowptr[i] = v;
    cursor[i] = v;
  }
}

__global__ __launch_bounds__(256) void k_scatter(const int* __restrict__ ei,
                                                 int E, int N,
                                                 int* __restrict__ cursor,
                                                 int* __restrict__ colbuf,
                                                 const int* __restrict__ flags) {
  int e = blockIdx.x * 256 + threadIdx.x;
  if (e < E) {
    int i64 = flags[1];
    int s = clampN(edge_src(ei, e, E, i64), N);
    int d = clampN(edge_dst(ei, e, E, i64), N);
    int p = atomicAdd(&cursor[d], 1);
    if (p >= 0 && p < E) colbuf[p] = s;
  }
}

// ---------------- projection ----------------
// One wave per node; lanes 0..31 = content outputs (K=768), 32..63 = style
// (K=128). x loads are wave-broadcast (same addr per half), W loads coalesced.
template <bool BF>
static __device__ void project_body(const void* xc, const void* xs,
                                    const void* Wp, const void* bp,
                                    const void* Ws, const void* bs,
                                    float* __restrict__ h0, int N) {
  int node = (int)((blockIdx.x * blockDim.x + threadIdx.x) >> 6);
  int lane = (int)(threadIdx.x & 63);
  if (node >= N) return;
  bool st = lane >= 32;
  int dd = lane & 31;
  const void* X = st ? xs : xc;
  const void* W = st ? Ws : Wp;
  const void* B = st ? bs : bp;
  int K = st ? 128 : 768;
  long long xo = (long long)node * K;
  float acc = ldf<BF>(B, dd);
  for (int k = 0; k < K; ++k)
    acc += ldf<BF>(X, xo + k) * ldf<BF>(W, (long long)k * 32 + dd);
  h0[(long long)node * 64 + lane] = acc;
}

__global__ __launch_bounds__(256) void k_project(
    const void* xc, const void* xs, const void* Wp, const void* bp,
    const void* Ws, const void* bs, float* h0, int N,
    const int* __restrict__ flags) {
  if (flags[0])
    project_body<true>(xc, xs, Wp, bp, Ws, bs, h0, N);
  else
    project_body<false>(xc, xs, Wp, bp, Ws, bs, h0, N);
}

// ---------------- SAGE layer ----------------
template <bool BF>
static __device__ void layer_body(const float* __restrict__ hin,
                                  const int* __restrict__ rowptr,
                                  const int* __restrict__ colbuf,
                                  const void* Wl, const void* bl,
                                  const void* Wr, float* __restrict__ hout,
                                  int N, int last, const void* Wo,
                                  const void* bo, void* outp) {
  int node = (int)((blockIdx.x * blockDim.x + threadIdx.x) >> 6);
  int lane = (int)(threadIdx.x & 63);
  if (node >= N) return;
  int rs = rowptr[node], re = rowptr[node + 1];
  float xself = hin[(long long)node * 64 + lane];
  float agg = 0.f;
  for (int cb = rs; cb < re; cb += 64) {
    int sidx = 0;
    if (cb + lane < re) sidx = clampN(colbuf[cb + lane], N);
    int c = re - cb;
    if (c > 64) c = 64;
    for (int t = 0; t < c; ++t) {
      int s = __builtin_amdgcn_readlane(sidx, t);
      agg += hin[(long long)s * 64 + lane];
    }
  }
  int deg = re - rs;
  if (deg > 0) agg *= (1.f / (float)deg);

  float o = ldf<BF>(bl, lane);
#pragma unroll 8
  for (int d = 0; d < 64; ++d) {
    float ad = __uint_as_float(
        __builtin_amdgcn_readlane(__float_as_uint(agg), d));
    float xd = __uint_as_float(
        __builtin_amdgcn_readlane(__float_as_uint(xself), d));
    o += ad * ldf<BF>(Wl, d * 64 + lane);
    o += xd * ldf<BF>(Wr, d * 64 + lane);
  }
  o = fmaxf(o, 0.f);

  if (!last) {
    hout[(long long)node * 64 + lane] = o;
  } else {
    float c0 = o * ldf<BF>(Wo, lane * 2 + 0);
    float c1 = o * ldf<BF>(Wo, lane * 2 + 1);
    for (int off = 32; off > 0; off >>= 1) {
      c0 += __shfl_xor(c0, off, 64);
      c1 += __shfl_xor(c1, off, 64);
    }
    if (lane == 0) {
      float r0 = c0 + ldf<BF>(bo, 0);
      float r1 = c1 + ldf<BF>(bo, 1);
      if (BF) {
        unsigned short* o16 = (unsigned short*)outp;
        o16[(long long)node * 2 + 0] = f2bf(r0);
        o16[(long long)node * 2 + 1] = f2bf(r1);
      } else {
        float* o32 = (float*)outp;
        o32[(long long)node * 2 + 0] = r0;
        o32[(long long)node * 2 + 1] = r1;
      }
    }
  }
}

__global__ __launch_bounds__(256) void k_layer(
    const float* hin, const int* rowptr, const int* colbuf, const void* Wl,
    const void* bl, const void* Wr, float* hout, int N, int last,
    const void* Wo, const void* bo, void* outp, const int* __restrict__ flags) {
  if (flags[0])
    layer_body<true>(hin, rowptr, colbuf, Wl, bl, Wr, hout, N, last, Wo, bo,
                     outp);
  else
    layer_body<false>(hin, rowptr, colbuf, Wl, bl, Wr, hout, N, last, Wo, bo,
                      outp);
}

// ---------------- host ----------------

extern "C" void kernel_launch(void* const* d_in, const int* in_sizes, int n_in,
                              void* d_out, int out_size, void* d_ws,
                              size_t ws_size, hipStream_t stream) {
  const void* xc = d_in[0];
  const void* xs = d_in[1];
  const int* ei = (const int*)d_in[2];
  const void* Wp = d_in[4];
  const void* bp = d_in[5];
  const void* Ws = d_in[6];
  const void* bs = d_in[7];
  const void* Wl1 = d_in[8];
  const void* bl1 = d_in[9];
  const void* Wr1 = d_in[10];
  const void* Wl2 = d_in[11];
  const void* bl2 = d_in[12];
  const void* Wr2 = d_in[13];
  const void* Wl3 = d_in[14];
  const void* bl3 = d_in[15];
  const void* Wr3 = d_in[16];
  const void* Wo = d_in[17];
  const void* bo = d_in[18];

  int N = out_size / 2;   // output is [N, 2] — robust to in_sizes semantics
  int E = in_sizes[3];    // edge_type has E elements

  char* ws = (char*)d_ws;
  size_t off = 0;
  auto alloc = [&](size_t bytes) {
    char* p = ws + off;
    off += (bytes + 255) & ~(size_t)255;
    return p;
  };
  // index data first (bounded consumers), float tables last
  int* colbuf = (int*)alloc((size_t)E * 4);
  int* cnt = (int*)alloc((size_t)N * 4);
  int* rowptr = (int*)alloc((size_t)(N + 1) * 4);
  int* cursor = (int*)alloc((size_t)N * 4);
  int* bsum = (int*)alloc(4096);
  int* flags = (int*)alloc(256);
  float* h0 = (float*)alloc((size_t)N * 64 * 4);
  float* h1 = (float*)alloc((size_t)N * 64 * 4);
  (void)ws_size;
  (void)n_in;

  k_detect<<<1, 64, 0, stream>>>(Wp, ei, flags);

  hipMemsetAsync(cnt, 0, (size_t)N * 4, stream);
  int eb = (E + 255) / 256;
  k_deg<<<eb, 256, 0, stream>>>(ei, E, N, cnt, flags);
  int sb = (N + 1023) / 1024;
  k_scan1<<<sb, 256, 0, stream>>>(cnt, rowptr, bsum, N);
  k_scan2<<<1, 64, 0, stream>>>(bsum, sb, rowptr, N);
  k_scan3<<<(N + 255) / 256, 256, 0, stream>>>(rowptr, cursor, bsum, N);
  k_scatter<<<eb, 256, 0, stream>>>(ei, E, N, cursor, colbuf, flags);

  int nb4 = (N + 3) / 4;  // 4 waves (nodes) per 256-thread block
  k_project<<<nb4, 256, 0, stream>>>(xc, xs, Wp, bp, Ws, bs, h0, N, flags);

  k_layer<<<nb4, 256, 0, stream>>>(h0, rowptr, colbuf, Wl1, bl1, Wr1, h1, N, 0,
                                   nullptr, nullptr, nullptr, flags);
  k_layer<<<nb4, 256, 0, stream>>>(h1, rowptr, colbuf, Wl2, bl2, Wr2, h0, N, 0,
                                   nullptr, nullptr, nullptr, flags);
  k_layer<<<nb4, 256, 0, stream>>>(h0, rowptr, colbuf, Wl3, bl3, Wr3, h1, N, 1,
                                   Wo, bo, d_out, flags);
}

// Round 3
// 1232.744 us; speedup vs baseline: 1.6646x; 1.6646x over previous
//
#include <hip/hip_runtime.h>
#include <stdint.h>

// ---------------------------------------------------------------------------
// FakeNewsModel: 3-layer GraphSAGE (mean agg), N=50000, E=1.6M, width 64.
// Round 3: fast k_project (thread = node x out-pair, 16B x loads, 4B W-pair
// loads). Everything else identical to the passing round-2 kernel.
//   k_detect  -> flags[0]=floats-are-bf16?, flags[1]=ints-are-int64?
//   CSR build -> memset(cnt), k_deg, k_scan1/2/3, k_scatter
//   k_project -> x0 = concat(xc@Wp+bp, xs@Ws+bs)  (fp32 h-table)
//   k_layer x3 -> relu(mean-agg@Wl + bl + x@Wr); layer 3 fuses [64,2] head.
// ---------------------------------------------------------------------------

typedef __attribute__((ext_vector_type(8))) unsigned short u16x8;
typedef __attribute__((ext_vector_type(4))) float f32x4;

static __device__ __forceinline__ float bf2f(unsigned short u) {
  union { unsigned int i; float f; } v;
  v.i = ((unsigned int)u) << 16;
  return v.f;
}

static __device__ __forceinline__ unsigned short f2bf(float f) {
  union { float f; unsigned int i; } v;
  v.f = f;
  unsigned int u = v.i;
  unsigned int r = (u + 0x7FFFu + ((u >> 16) & 1u)) >> 16;  // RNE
  return (unsigned short)r;
}

template <bool BF>
static __device__ __forceinline__ float ldf(const void* p, long long i) {
  if (BF) return bf2f(((const unsigned short*)p)[i]);
  return ((const float*)p)[i];
}

// 8 consecutive floats starting at element idx (16B-aligned in bf16 world).
template <bool BF>
static __device__ __forceinline__ void load8(const void* p, long long idx,
                                             float* out) {
  if (BF) {
    u16x8 v = *(const u16x8*)((const unsigned short*)p + idx);
#pragma unroll
    for (int j = 0; j < 8; ++j) out[j] = bf2f(v[j]);
  } else {
    f32x4 a = *(const f32x4*)((const float*)p + idx);
    f32x4 b = *(const f32x4*)((const float*)p + idx + 4);
#pragma unroll
    for (int j = 0; j < 4; ++j) {
      out[j] = a[j];
      out[4 + j] = b[j];
    }
  }
}

// two consecutive weights at element idx (idx even -> one 4B load in bf16).
template <bool BF>
static __device__ __forceinline__ void loadw2(const void* p, long long idx,
                                              float& w0, float& w1) {
  if (BF) {
    unsigned int u = *(const unsigned int*)((const unsigned short*)p + idx);
    union { unsigned int i; float f; } c0, c1;
    c0.i = u << 16;
    c1.i = u & 0xFFFF0000u;
    w0 = c0.f;
    w1 = c1.f;
  } else {
    const float* f = (const float*)p + idx;
    w0 = f[0];
    w1 = f[1];
  }
}

static __device__ __forceinline__ int clampN(int v, int N) {
  return v < 0 ? 0 : (v >= N ? N - 1 : v);
}

// ---------------- dtype detection ----------------
__global__ void k_detect(const void* Wp, const int* ei, int* flags) {
  if (threadIdx.x == 0 && blockIdx.x == 0) {
    const unsigned short* w = (const unsigned short*)Wp;
    int bf = 1;
    for (int i = 0; i < 64; ++i) {
      float v = fabsf(bf2f(w[i]));
      if (!(v < 1.0f)) bf = 0;  // catches NaN too
    }
    flags[0] = bf;
    int i64 = 1;
    for (int i = 0; i < 32; ++i)
      if (ei[2 * i + 1] != 0) i64 = 0;
    flags[1] = i64;
  }
}

static __device__ __forceinline__ int edge_src(const int* ei, int e, int E,
                                               int i64) {
  return i64 ? ei[2 * (long long)e] : ei[e];
}
static __device__ __forceinline__ int edge_dst(const int* ei, int e, int E,
                                               int i64) {
  return i64 ? ei[2 * ((long long)E + e)] : ei[(long long)E + e];
}

// ---------------- CSR build ----------------

__global__ __launch_bounds__(256) void k_deg(const int* __restrict__ ei, int E,
                                             int N, int* __restrict__ cnt,
                                             const int* __restrict__ flags) {
  int e = blockIdx.x * 256 + threadIdx.x;
  if (e < E) {
    int d = clampN(edge_dst(ei, e, E, flags[1]), N);
    atomicAdd(&cnt[d], 1);
  }
}

__global__ __launch_bounds__(256) void k_scan1(const int* __restrict__ cnt,
                                               int* __restrict__ rowptr,
                                               int* __restrict__ bsum, int N) {
  __shared__ int sh[256];
  int t = threadIdx.x;
  int base = blockIdx.x * 1024 + t * 4;
  int v0 = 0, v1 = 0, v2 = 0, v3 = 0;
  if (base + 0 < N) v0 = cnt[base + 0];
  if (base + 1 < N) v1 = cnt[base + 1];
  if (base + 2 < N) v2 = cnt[base + 2];
  if (base + 3 < N) v3 = cnt[base + 3];
  int s = v0 + v1 + v2 + v3;
  sh[t] = s;
  __syncthreads();
  int acc = s;
  for (int off = 1; off < 256; off <<= 1) {
    int x = 0;
    if (t >= off) x = sh[t - off];
    __syncthreads();
    acc += x;
    sh[t] = acc;
    __syncthreads();
  }
  int run = acc - s;
  if (base + 0 < N) rowptr[base + 0] = run;
  run += v0;
  if (base + 1 < N) rowptr[base + 1] = run;
  run += v1;
  if (base + 2 < N) rowptr[base + 2] = run;
  run += v2;
  if (base + 3 < N) rowptr[base + 3] = run;
  run += v3;
  if (t == 255) bsum[blockIdx.x] = acc;
}

__global__ void k_scan2(int* __restrict__ bsum, int nb,
                        int* __restrict__ rowptr, int N) {
  if (threadIdx.x == 0 && blockIdx.x == 0) {
    int run = 0;
    for (int i = 0; i < nb; ++i) {
      int v = bsum[i];
      bsum[i] = run;
      run += v;
    }
    rowptr[N] = run;
  }
}

__global__ __launch_bounds__(256) void k_scan3(int* __restrict__ rowptr,
                                               int* __restrict__ cursor,
                                               const int* __restrict__ bsum,
                                               int N) {
  int i = blockIdx.x * 256 + threadIdx.x;
  if (i < N) {
    int v = rowptr[i] + bsum[i >> 10];
    rowptr[i] = v;
    cursor[i] = v;
  }
}

__global__ __launch_bounds__(256) void k_scatter(const int* __restrict__ ei,
                                                 int E, int N,
                                                 int* __restrict__ cursor,
                                                 int* __restrict__ colbuf,
                                                 const int* __restrict__ flags) {
  int e = blockIdx.x * 256 + threadIdx.x;
  if (e < E) {
    int i64 = flags[1];
    int s = clampN(edge_src(ei, e, E, i64), N);
    int d = clampN(edge_dst(ei, e, E, i64), N);
    int p = atomicAdd(&cursor[d], 1);
    if (p >= 0 && p < E) colbuf[p] = s;
  }
}

// ---------------- projection (v2) ----------------
// 16 nodes per 256-thread block; thread (node, o) computes output columns
// {2o, 2o+1} of content (K=768) and of style (K=128). x loads: 16B ushort8,
// wave-broadcast within each node's 16 threads. W loads: one 4B dword per
// (k, out-pair) — coalesced 64B per node-group, L1-resident.
template <bool BF>
static __device__ void project_body(const void* xc, const void* xs,
                                    const void* Wp, const void* bp,
                                    const void* Ws, const void* bs,
                                    float* __restrict__ h0, int N) {
  int t = (int)threadIdx.x;
  int node = (int)blockIdx.x * 16 + (t >> 4);
  int o2 = (t & 15) * 2;
  if (node >= N) return;

  float c0 = 0.f, c1 = 0.f, s0 = 0.f, s1 = 0.f;

  long long xoff = (long long)node * 768;
#pragma unroll 2
  for (int k = 0; k < 768; k += 8) {
    float xv[8];
    load8<BF>(xc, xoff + k, xv);
#pragma unroll
    for (int j = 0; j < 8; ++j) {
      float w0, w1;
      loadw2<BF>(Wp, (long long)(k + j) * 32 + o2, w0, w1);
      c0 += xv[j] * w0;
      c1 += xv[j] * w1;
    }
  }

  long long soff = (long long)node * 128;
#pragma unroll 2
  for (int k = 0; k < 128; k += 8) {
    float xv[8];
    load8<BF>(xs, soff + k, xv);
#pragma unroll
    for (int j = 0; j < 8; ++j) {
      float w0, w1;
      loadw2<BF>(Ws, (long long)(k + j) * 32 + o2, w0, w1);
      s0 += xv[j] * w0;
      s1 += xv[j] * w1;
    }
  }

  float* orow = h0 + (long long)node * 64;
  orow[o2 + 0] = c0 + ldf<BF>(bp, o2 + 0);
  orow[o2 + 1] = c1 + ldf<BF>(bp, o2 + 1);
  orow[32 + o2 + 0] = s0 + ldf<BF>(bs, o2 + 0);
  orow[32 + o2 + 1] = s1 + ldf<BF>(bs, o2 + 1);
}

__global__ __launch_bounds__(256) void k_project(
    const void* xc, const void* xs, const void* Wp, const void* bp,
    const void* Ws, const void* bs, float* h0, int N,
    const int* __restrict__ flags) {
  if (flags[0])
    project_body<true>(xc, xs, Wp, bp, Ws, bs, h0, N);
  else
    project_body<false>(xc, xs, Wp, bp, Ws, bs, h0, N);
}

// ---------------- SAGE layer ----------------
template <bool BF>
static __device__ void layer_body(const float* __restrict__ hin,
                                  const int* __restrict__ rowptr,
                                  const int* __restrict__ colbuf,
                                  const void* Wl, const void* bl,
                                  const void* Wr, float* __restrict__ hout,
                                  int N, int last, const void* Wo,
                                  const void* bo, void* outp) {
  int node = (int)((blockIdx.x * blockDim.x + threadIdx.x) >> 6);
  int lane = (int)(threadIdx.x & 63);
  if (node >= N) return;
  int rs = rowptr[node], re = rowptr[node + 1];
  float xself = hin[(long long)node * 64 + lane];
  float agg = 0.f;
  for (int cb = rs; cb < re; cb += 64) {
    int sidx = 0;
    if (cb + lane < re) sidx = clampN(colbuf[cb + lane], N);
    int c = re - cb;
    if (c > 64) c = 64;
    for (int t = 0; t < c; ++t) {
      int s = __builtin_amdgcn_readlane(sidx, t);
      agg += hin[(long long)s * 64 + lane];
    }
  }
  int deg = re - rs;
  if (deg > 0) agg *= (1.f / (float)deg);

  float o = ldf<BF>(bl, lane);
#pragma unroll 8
  for (int d = 0; d < 64; ++d) {
    float ad = __uint_as_float(
        __builtin_amdgcn_readlane(__float_as_uint(agg), d));
    float xd = __uint_as_float(
        __builtin_amdgcn_readlane(__float_as_uint(xself), d));
    o += ad * ldf<BF>(Wl, d * 64 + lane);
    o += xd * ldf<BF>(Wr, d * 64 + lane);
  }
  o = fmaxf(o, 0.f);

  if (!last) {
    hout[(long long)node * 64 + lane] = o;
  } else {
    float c0 = o * ldf<BF>(Wo, lane * 2 + 0);
    float c1 = o * ldf<BF>(Wo, lane * 2 + 1);
    for (int off = 32; off > 0; off >>= 1) {
      c0 += __shfl_xor(c0, off, 64);
      c1 += __shfl_xor(c1, off, 64);
    }
    if (lane == 0) {
      float r0 = c0 + ldf<BF>(bo, 0);
      float r1 = c1 + ldf<BF>(bo, 1);
      if (BF) {
        unsigned short* o16 = (unsigned short*)outp;
        o16[(long long)node * 2 + 0] = f2bf(r0);
        o16[(long long)node * 2 + 1] = f2bf(r1);
      } else {
        float* o32 = (float*)outp;
        o32[(long long)node * 2 + 0] = r0;
        o32[(long long)node * 2 + 1] = r1;
      }
    }
  }
}

__global__ __launch_bounds__(256) void k_layer(
    const float* hin, const int* rowptr, const int* colbuf, const void* Wl,
    const void* bl, const void* Wr, float* hout, int N, int last,
    const void* Wo, const void* bo, void* outp, const int* __restrict__ flags) {
  if (flags[0])
    layer_body<true>(hin, rowptr, colbuf, Wl, bl, Wr, hout, N, last, Wo, bo,
                     outp);
  else
    layer_body<false>(hin, rowptr, colbuf, Wl, bl, Wr, hout, N, last, Wo, bo,
                      outp);
}

// ---------------- host ----------------

extern "C" void kernel_launch(void* const* d_in, const int* in_sizes, int n_in,
                              void* d_out, int out_size, void* d_ws,
                              size_t ws_size, hipStream_t stream) {
  const void* xc = d_in[0];
  const void* xs = d_in[1];
  const int* ei = (const int*)d_in[2];
  const void* Wp = d_in[4];
  const void* bp = d_in[5];
  const void* Ws = d_in[6];
  const void* bs = d_in[7];
  const void* Wl1 = d_in[8];
  const void* bl1 = d_in[9];
  const void* Wr1 = d_in[10];
  const void* Wl2 = d_in[11];
  const void* bl2 = d_in[12];
  const void* Wr2 = d_in[13];
  const void* Wl3 = d_in[14];
  const void* bl3 = d_in[15];
  const void* Wr3 = d_in[16];
  const void* Wo = d_in[17];
  const void* bo = d_in[18];

  int N = out_size / 2;   // output is [N, 2]
  int E = in_sizes[3];    // edge_type has E elements

  char* ws = (char*)d_ws;
  size_t off = 0;
  auto alloc = [&](size_t bytes) {
    char* p = ws + off;
    off += (bytes + 255) & ~(size_t)255;
    return p;
  };
  int* colbuf = (int*)alloc((size_t)E * 4);
  int* cnt = (int*)alloc((size_t)N * 4);
  int* rowptr = (int*)alloc((size_t)(N + 1) * 4);
  int* cursor = (int*)alloc((size_t)N * 4);
  int* bsum = (int*)alloc(4096);
  int* flags = (int*)alloc(256);
  float* h0 = (float*)alloc((size_t)N * 64 * 4);
  float* h1 = (float*)alloc((size_t)N * 64 * 4);
  (void)ws_size;
  (void)n_in;

  k_detect<<<1, 64, 0, stream>>>(Wp, ei, flags);

  hipMemsetAsync(cnt, 0, (size_t)N * 4, stream);
  int eb = (E + 255) / 256;
  k_deg<<<eb, 256, 0, stream>>>(ei, E, N, cnt, flags);
  int sb = (N + 1023) / 1024;
  k_scan1<<<sb, 256, 0, stream>>>(cnt, rowptr, bsum, N);
  k_scan2<<<1, 64, 0, stream>>>(bsum, sb, rowptr, N);
  k_scan3<<<(N + 255) / 256, 256, 0, stream>>>(rowptr, cursor, bsum, N);
  k_scatter<<<eb, 256, 0, stream>>>(ei, E, N, cursor, colbuf, flags);

  int pb = (N + 15) / 16;  // 16 nodes per block
  k_project<<<pb, 256, 0, stream>>>(xc, xs, Wp, bp, Ws, bs, h0, N, flags);

  int nb4 = (N + 3) / 4;  // 4 waves (nodes) per 256-thread block
  k_layer<<<nb4, 256, 0, stream>>>(h0, rowptr, colbuf, Wl1, bl1, Wr1, h1, N, 0,
                                   nullptr, nullptr, nullptr, flags);
  k_layer<<<nb4, 256, 0, stream>>>(h1, rowptr, colbuf, Wl2, bl2, Wr2, h0, N, 0,
                                   nullptr, nullptr, nullptr, flags);
  k_layer<<<nb4, 256, 0, stream>>>(h0, rowptr, colbuf, Wl3, bl3, Wr3, h1, N, 1,
                                   Wo, bo, d_out, flags);
}